// Round 18
// baseline (166.670 us; speedup 1.0000x reference)
//
#include <hip/hip_runtime.h>
#include <stdint.h>

// ClusterHead: P = softmax_k( x . c_k - 0.5*||c_k||^2 )   (||x||^2 cancels)
// R18: SPLIT kernels. (1) gemm: R11 K-loop, epilogue = int16 logit store
// (round(128*x.c), courier'd into the first 2KB of each out row's region --
// row-self-contained, no extra workspace). No bias/barriers/reductions in
// the GEMM epilogue. (2) softmax: pure streaming, wave per row: read 2KB
// int16 logits + bias, 64-lane shfl softmax, NT-write 4KB fp32.
// Single-term fp16 GEMM (absmax 0.0078 validated), 32x32x16 f16 MFMA,
// A-panel staged once to LDS (XOR swizzle), barrier-free K-loop, B
// global->VGPR full-slice reg double-buffer, NT x loads.
// B-pack: 32 sub-images of 32KB; s = 2t + jh; within: [ks(2)][cb(16)]
// [(c32*2+kh)*8] halfwords.

namespace {
constexpr int N_ROWS  = 32768;
constexpr int K_CL    = 1024;
constexpr int D_DIM   = 512;
constexpr int BM      = 64;
constexpr int THREADS = 512;
constexpr int WAVES   = 8;
}

typedef _Float16 f16_t;
typedef _Float16 f16x8 __attribute__((ext_vector_type(8)));
typedef _Float16 f16x4 __attribute__((ext_vector_type(4)));
typedef short    s16x8 __attribute__((ext_vector_type(8)));
typedef float    f32x16 __attribute__((ext_vector_type(16)));
typedef float    f32x4v __attribute__((ext_vector_type(4)));

// ---- prep: fp16 B-pack + bias = -0.5*||c||^2 (fp32 exact) ----
__global__ __launch_bounds__(64) void prep_kernel(const float* __restrict__ centers,
                                                  f16_t* __restrict__ bpack,
                                                  float* __restrict__ bias) {
  const int col = blockIdx.x, lane = threadIdx.x;
  const int t  = lane >> 2;          // k-slice of this lane's 8 d's
  const int ks = (lane >> 1) & 1;    // 16-k group
  const int kh = lane & 1;           // 8-k half
  const float* src = centers + (size_t)col * D_DIM + lane * 8;
  f16x8 hi;
  float ssq = 0.f;
  #pragma unroll
  for (int i = 0; i < 8; ++i) {
    float v = src[i];
    ssq += v * v;
    hi[i] = (f16_t)v;
  }
  const int jh = col >> 9, cb = (col & 511) >> 5, c32 = col & 31;
  const size_t off = ((size_t)ks * 16 + cb) * 512 + (c32 * 2 + kh) * 8;  // halfwords
  *(f16x8*)(bpack + (size_t)(2 * t + jh) * 16384 + off) = hi;
  for (int o = 32; o; o >>= 1) ssq += __shfl_down(ssq, o, 64);
  if (lane == 0) bias[col] = -0.5f * ssq;
}

// ---- GEMM kernel: 64 rows x 1024 cols per block, int16 logit epilogue ----
__global__ __launch_bounds__(THREADS, 2) void gemm_kernel(
    const float* __restrict__ x, const f16_t* __restrict__ bpack,
    float* __restrict__ out) {
  __shared__ __align__(16) char Ax[64 * 1024];   // 64KB swizzled A panel

  const int tid  = threadIdx.x;
  const int wid  = tid >> 6;
  const int lane = tid & 63;
  const int l31  = lane & 31;
  const int h    = lane >> 5;
  const int brow = blockIdx.x * BM;

  // per-lane byte base into a B sub-image (wave's 2 cb-blocks at wid*2048)
  const char* bbase = (const char*)bpack + wid * 2048 + (l31 * 2 + h) * 16;

#define LOADB8(S, DST)                                                         \
  {                                                                            \
    const char* p_ = bbase + (size_t)((S) & 31) * 32768;                       \
    (DST)[0] = *(const f16x8*)(p_);            /* jh0 ks0 cb-even */           \
    (DST)[1] = *(const f16x8*)(p_ + 1024);     /* jh0 ks0 cb-odd  */           \
    (DST)[2] = *(const f16x8*)(p_ + 16384);    /* jh0 ks1 cb-even */           \
    (DST)[3] = *(const f16x8*)(p_ + 17408);    /* jh0 ks1 cb-odd  */           \
    (DST)[4] = *(const f16x8*)(p_ + 32768);    /* jh1 ks0 cb-even */           \
    (DST)[5] = *(const f16x8*)(p_ + 33792);    /* jh1 ks0 cb-odd  */           \
    (DST)[6] = *(const f16x8*)(p_ + 49152);    /* jh1 ks1 cb-even */           \
    (DST)[7] = *(const f16x8*)(p_ + 50176);    /* jh1 ks1 cb-odd  */           \
  }
#define COMPUTE16(B)                                                           \
  {                                                                            \
    _Pragma("unroll")                                                          \
    for (int j2_ = 0; j2_ < 2; ++j2_)                                          \
      _Pragma("unroll")                                                        \
      for (int ks_ = 0; ks_ < 2; ++ks_)                                        \
        _Pragma("unroll")                                                      \
        for (int c2_ = 0; c2_ < 2; ++c2_)                                      \
          _Pragma("unroll")                                                    \
          for (int rb_ = 0; rb_ < 2; ++rb_)                                    \
            acc[rb_][j2_ * 2 + c2_] = __builtin_amdgcn_mfma_f32_32x32x16_f16(  \
                a[rb_][ks_], (B)[j2_ * 4 + ks_ * 2 + c2_],                     \
                acc[rb_][j2_ * 2 + c2_], 0, 0, 0);                             \
  }

  f16x8 bA[8], bB[8];

  // issue first slice's B loads before staging (covers L2 latency)
  LOADB8(0, bA)

  // ---- stage x panel -> LDS fp16 (coalesced NT reads, swizzled writes) ----
  {
    const float* xsrc = x + (size_t)brow * D_DIM;
    #pragma unroll
    for (int it = 0; it < 16; ++it) {
      const int idx = it * 512 + tid;            // float4 index
      const int r = idx >> 7, f = idx & 127;
      f32x4v v = __builtin_nontemporal_load(
          (const f32x4v*)(xsrc + (size_t)r * D_DIM + f * 4));
      f16x4 h4;
      h4[0] = (f16_t)v[0]; h4[1] = (f16_t)v[1];
      h4[2] = (f16_t)v[2]; h4[3] = (f16_t)v[3];
      *(f16x4*)(Ax + r * 1024 + ((f * 8) ^ ((r & 7) << 4))) = h4;
    }
  }
  __syncthreads();   // the ONLY barrier in this kernel

  f32x16 acc[2][4];
  #pragma unroll
  for (int rb = 0; rb < 2; ++rb)
    #pragma unroll
    for (int cc = 0; cc < 4; ++cc)
      #pragma unroll
      for (int e = 0; e < 16; ++e) acc[rb][cc][e] = 0.f;

  const char* abase0 = Ax + l31 * 1024;          // rb=0 rows; rb=1 at +32KB
  const int swz = (l31 & 7) << 4;
  const int h16 = h * 16;
  f16x8 a[2][2];

  // ---- main loop: 16 slices, barrier-free ----
  #pragma unroll
  for (int tt = 0; tt < 8; ++tt) {
    {  // slice T = 2*tt : compute bA, prefetch bB
      const int T = 2 * tt;
      LOADB8(2 * (T + 1), bB)
      const int o0 = (T * 64 + h16) ^ swz;
      const int o1 = o0 ^ 32;
      a[0][0] = *(const f16x8*)(abase0 + o0);
      a[0][1] = *(const f16x8*)(abase0 + o1);
      a[1][0] = *(const f16x8*)(abase0 + 32768 + o0);
      a[1][1] = *(const f16x8*)(abase0 + 32768 + o1);
      COMPUTE16(bA)
    }
    {  // slice T = 2*tt+1 : compute bB, prefetch bA
      const int T = 2 * tt + 1;
      if (T < 15) LOADB8(2 * (T + 1), bA)
      const int o0 = (T * 64 + h16) ^ swz;
      const int o1 = o0 ^ 32;
      a[0][0] = *(const f16x8*)(abase0 + o0);
      a[0][1] = *(const f16x8*)(abase0 + o1);
      a[1][0] = *(const f16x8*)(abase0 + 32768 + o0);
      a[1][1] = *(const f16x8*)(abase0 + 32768 + o1);
      COMPUTE16(bB)
    }
  }

  // ---- epilogue: int16 logit store into row-region courier (first 2KB) ----
  // col(cc) = (cc>>1)*512 + wid*64 + (cc&1)*32 + l31
  // row(rb,reg) = rb*32 + (reg&3) + 8*(reg>>2) + 4*h
  #pragma unroll
  for (int rb = 0; rb < 2; ++rb)
    #pragma unroll
    for (int reg = 0; reg < 16; ++reg) {
      const int row = rb * 32 + (reg & 3) + 8 * (reg >> 2) + 4 * h;
      short* lp = (short*)(out + (size_t)(brow + row) * K_CL);
      #pragma unroll
      for (int cc = 0; cc < 4; ++cc) {
        const int col = (cc >> 1) * 512 + wid * 64 + (cc & 1) * 32 + l31;
        float v = acc[rb][cc][reg] * 128.f;
        v = fminf(fmaxf(v, -32000.f), 32000.f);
        lp[col] = (short)__float2int_rn(v);
      }
    }
}

// ---- softmax kernel: wave per row, pure streaming ----
__global__ __launch_bounds__(256) void softmax_kernel(
    const float* __restrict__ bias, float* __restrict__ out) {
  const int tid  = threadIdx.x;
  const int row  = blockIdx.x * 4 + (tid >> 6);
  const int lane = tid & 63;

  float* rp = out + (size_t)row * K_CL;
  const short* lp = (const short*)rp + lane * 16;   // this lane's 16 logits
  s16x8 q0 = *(const s16x8*)(lp);
  s16x8 q1 = *(const s16x8*)(lp + 8);

  const float* bp = bias + lane * 16;
  float v[16];
  #pragma unroll
  for (int i = 0; i < 8; ++i) {
    v[i]     = (float)q0[i] * (1.f / 128.f) + bp[i];
    v[i + 8] = (float)q1[i] * (1.f / 128.f) + bp[i + 8];
  }

  float m = v[0];
  #pragma unroll
  for (int i = 1; i < 16; ++i) m = fmaxf(m, v[i]);
  m = fmaxf(m, __shfl_xor(m, 1, 64));
  m = fmaxf(m, __shfl_xor(m, 2, 64));
  m = fmaxf(m, __shfl_xor(m, 4, 64));
  m = fmaxf(m, __shfl_xor(m, 8, 64));
  m = fmaxf(m, __shfl_xor(m, 16, 64));
  m = fmaxf(m, __shfl_xor(m, 32, 64));

  float s = 0.f;
  #pragma unroll
  for (int i = 0; i < 16; ++i) {
    v[i] = __expf(v[i] - m);
    s += v[i];
  }
  s += __shfl_xor(s, 1, 64);
  s += __shfl_xor(s, 2, 64);
  s += __shfl_xor(s, 4, 64);
  s += __shfl_xor(s, 8, 64);
  s += __shfl_xor(s, 16, 64);
  s += __shfl_xor(s, 32, 64);
  const float rinv = 1.f / s;

  float* wp = rp + lane * 16;
  #pragma unroll
  for (int j = 0; j < 4; ++j) {
    f32x4v w;
    w[0] = v[j * 4 + 0] * rinv;
    w[1] = v[j * 4 + 1] * rinv;
    w[2] = v[j * 4 + 2] * rinv;
    w[3] = v[j * 4 + 3] * rinv;
    __builtin_nontemporal_store(w, (f32x4v*)(wp + j * 4));
  }
}

extern "C" void kernel_launch(void* const* d_in, const int* in_sizes, int n_in,
                              void* d_out, int out_size, void* d_ws, size_t ws_size,
                              hipStream_t stream) {
  const float* x       = (const float*)d_in[0];   // [32768, 512] fp32
  const float* centers = (const float*)d_in[1];   // [1024, 512] fp32
  float* out = (float*)d_out;                     // [32768, 1024] fp32

  f16_t* bpack = (f16_t*)d_ws;                                   // 32*32KB = 1MB
  float* bias  = (float*)((char*)d_ws + (size_t)32 * 32768);     // 4KB

  prep_kernel<<<K_CL, 64, 0, stream>>>(centers, bpack, bias);
  gemm_kernel<<<N_ROWS / BM, THREADS, 0, stream>>>(x, bpack, out);
  softmax_kernel<<<N_ROWS / 4, 256, 0, stream>>>(bias, out);
}